// Round 3
// baseline (479.844 us; speedup 1.0000x reference)
//
#include <hip/hip_runtime.h>
#include <stdint.h>

typedef unsigned short u16;
typedef unsigned int u32;
typedef int v4i __attribute__((ext_vector_type(4)));
typedef float v4f __attribute__((ext_vector_type(4)));
typedef short v8s __attribute__((ext_vector_type(8)));

#define Bn 2
#define Tn 2048
#define Cn 2048
#define Hn 16
#define HDn 128

__device__ __forceinline__ float b2f(u16 u) {
    u32 x = ((u32)u) << 16;
    float f;
    __builtin_memcpy(&f, &x, 4);
    return f;
}
__device__ __forceinline__ u16 f2b(float f) {
    u32 x;
    __builtin_memcpy(&x, &f, 4);
    u32 r = (x + 0x7fffu + ((x >> 16) & 1u)) >> 16;
    return (u16)r;
}

__device__ __forceinline__ void async16(const void* g, void* l) {
    __builtin_amdgcn_global_load_lds(
        (const __attribute__((address_space(1))) u32*)g,
        (__attribute__((address_space(3))) u32*)l, 16, 0, 0);
}

// ---------- row quantization: X[R][2048] fp32 -> int8 + scale ----------
__global__ __launch_bounds__(256) void quant_rows(const float* __restrict__ X,
                                                  int8_t* __restrict__ Q,
                                                  float* __restrict__ S) {
    int r = blockIdx.x;
    const float* x = X + (size_t)r * Cn;
    int tid = threadIdx.x;
    float4 v0 = ((const float4*)x)[tid * 2];
    float4 v1 = ((const float4*)x)[tid * 2 + 1];
    float a[8] = {v0.x, v0.y, v0.z, v0.w, v1.x, v1.y, v1.z, v1.w};
    float m = 0.f;
#pragma unroll
    for (int i = 0; i < 8; i++) m = fmaxf(m, fabsf(a[i]));
#pragma unroll
    for (int o = 32; o; o >>= 1) m = fmaxf(m, __shfl_xor(m, o));
    __shared__ float sm[4];
    if ((tid & 63) == 0) sm[tid >> 6] = m;
    __syncthreads();
    m = fmaxf(fmaxf(sm[0], sm[1]), fmaxf(sm[2], sm[3]));
    float s = m * (1.0f / 127.0f) + 1e-8f;
    if (tid == 0) S[r] = s;
    u32 lo = 0, hi = 0;
#pragma unroll
    for (int i = 0; i < 8; i++) {
        float q = rintf(fminf(127.f, fmaxf(-127.f, a[i] / s)));
        int qi = (int)q;
        u32 byte = (u32)(qi & 0xff);
        if (i < 4) lo |= byte << (8 * i);
        else hi |= byte << (8 * (i - 4));
    }
    u32* qp = (u32*)(Q + (size_t)r * Cn);
    qp[tid * 2] = lo;
    qp[tid * 2 + 1] = hi;
}

// ---------- int8 GEMM: C[m][n] = (A[m][:] . B[n][:]) * sA[m]*sB[n]
// M=4096, N=2048, K=2048 fixed. 128x128 tile, BK=64, 4 waves.
// fp32out=0: write bf16 (u16). fp32out=1: write fp32.
__global__ __launch_bounds__(256) void gemm_i8(
    const int8_t* __restrict__ A, const int8_t* __restrict__ Bw,
    const float* __restrict__ sA, const float* __restrict__ sB,
    void* __restrict__ Co, long long bStride, long long sbStride,
    long long cStride, int fp32out) {
    int z = blockIdx.z;
    Bw += (size_t)z * bStride;
    sB += (size_t)z * sbStride;
    const int K = 2048, N = 2048;
    __shared__ int8_t As[128 * 64];
    __shared__ int8_t Bs[128 * 64];
    int m0 = blockIdx.x * 128, n0 = blockIdx.y * 128;
    int tid = threadIdx.x, w = tid >> 6, lane = tid & 63;
    int quad = lane >> 4, l15 = lane & 15;
    int wy = w >> 1, wx = w & 1;
    const v4i zi = {0, 0, 0, 0};
    v4i acc[4][4];
#pragma unroll
    for (int i = 0; i < 4; i++)
#pragma unroll
        for (int j = 0; j < 4; j++) acc[i][j] = zi;
    int srow = w * 32 + (lane >> 2);
    int kb = (lane & 3) * 16;
    const int8_t* ga = A + (size_t)(m0 + srow) * K + kb;
    const int8_t* gb = Bw + (size_t)(n0 + srow) * K + kb;
    int8_t* la = &As[srow * 64 + kb];
    int8_t* lb = &Bs[srow * 64 + kb];
    for (int k0 = 0; k0 < K; k0 += 64) {
        async16(ga + k0, la);
        async16(ga + k0 + (size_t)16 * K, la + 16 * 64);
        async16(gb + k0, lb);
        async16(gb + k0 + (size_t)16 * K, lb + 16 * 64);
        __syncthreads();
        v4i af[4], bf4[4];
#pragma unroll
        for (int i = 0; i < 4; i++)
            af[i] = *(const v4i*)&As[(wy * 64 + i * 16 + l15) * 64 + quad * 16];
#pragma unroll
        for (int j = 0; j < 4; j++)
            bf4[j] = *(const v4i*)&Bs[(wx * 64 + j * 16 + l15) * 64 + quad * 16];
#pragma unroll
        for (int i = 0; i < 4; i++)
#pragma unroll
            for (int j = 0; j < 4; j++)
                acc[i][j] = __builtin_amdgcn_mfma_i32_16x16x64_i8(
                    af[i], bf4[j], acc[i][j], 0, 0, 0);
        __syncthreads();
    }
#pragma unroll
    for (int i = 0; i < 4; i++) {
        int mb = m0 + wy * 64 + i * 16 + quad * 4;
        float s0 = sA[mb], s1 = sA[mb + 1], s2 = sA[mb + 2], s3 = sA[mb + 3];
#pragma unroll
        for (int j = 0; j < 4; j++) {
            int n = n0 + wx * 64 + j * 16 + l15;
            float sb = sB[n];
            if (fp32out) {
                float* cp = (float*)Co + (size_t)cStride * z + (size_t)mb * N + n;
                cp[0] = (float)acc[i][j][0] * s0 * sb;
                cp[N] = (float)acc[i][j][1] * s1 * sb;
                cp[2 * N] = (float)acc[i][j][2] * s2 * sb;
                cp[3 * N] = (float)acc[i][j][3] * s3 * sb;
            } else {
                u16* cp = (u16*)Co + (size_t)cStride * z + (size_t)mb * N + n;
                cp[0] = f2b((float)acc[i][j][0] * s0 * sb);
                cp[N] = f2b((float)acc[i][j][1] * s1 * sb);
                cp[2 * N] = f2b((float)acc[i][j][2] * s2 * sb);
                cp[3 * N] = f2b((float)acc[i][j][3] * s3 * sb);
            }
        }
    }
}

// ---------- fused RMSNorm (full 2048-dim row) + interleaved RoPE, in-place bf16
__global__ __launch_bounds__(256) void norm_rope(u16* __restrict__ X,
                                                 const float* __restrict__ g,
                                                 const float* __restrict__ cs,
                                                 const float* __restrict__ sn) {
    int row = blockIdx.x;
    int t = row & (Tn - 1);
    u16* x = X + (size_t)row * Cn;
    int tid = threadIdx.x;
    uint4 raw = ((const uint4*)x)[tid];
    u16 us[8];
    us[0] = raw.x & 0xffff; us[1] = raw.x >> 16;
    us[2] = raw.y & 0xffff; us[3] = raw.y >> 16;
    us[4] = raw.z & 0xffff; us[5] = raw.z >> 16;
    us[6] = raw.w & 0xffff; us[7] = raw.w >> 16;
    float v[8];
#pragma unroll
    for (int i = 0; i < 8; i++) v[i] = b2f(us[i]);
    float ss = 0.f;
#pragma unroll
    for (int i = 0; i < 8; i++) ss += v[i] * v[i];
#pragma unroll
    for (int o = 32; o; o >>= 1) ss += __shfl_xor(ss, o);
    __shared__ float sm[4];
    if ((tid & 63) == 0) sm[tid >> 6] = ss;
    __syncthreads();
    ss = sm[0] + sm[1] + sm[2] + sm[3];
    float r = rsqrtf(ss * (1.f / 2048.f) + 1e-6f);
    float4 g0 = ((const float4*)g)[tid * 2];
    float4 g1 = ((const float4*)g)[tid * 2 + 1];
    float n[8];
    n[0] = v[0] * r * g0.x; n[1] = v[1] * r * g0.y;
    n[2] = v[2] * r * g0.z; n[3] = v[3] * r * g0.w;
    n[4] = v[4] * r * g1.x; n[5] = v[5] * r * g1.y;
    n[6] = v[6] * r * g1.z; n[7] = v[7] * r * g1.w;
    int pi = (tid & 15) * 4;  // pair index within head, 4 consecutive pairs
    float4 c4 = *(const float4*)(cs + t * 64 + pi);
    float4 s4 = *(const float4*)(sn + t * 64 + pi);
    float o[8];
    o[0] = n[0] * c4.x - n[1] * s4.x; o[1] = n[0] * s4.x + n[1] * c4.x;
    o[2] = n[2] * c4.y - n[3] * s4.y; o[3] = n[2] * s4.y + n[3] * c4.y;
    o[4] = n[4] * c4.z - n[5] * s4.z; o[5] = n[4] * s4.z + n[5] * c4.z;
    o[6] = n[6] * c4.w - n[7] * s4.w; o[7] = n[6] * s4.w + n[7] * c4.w;
    uint4 out;
    out.x = (u32)f2b(o[0]) | ((u32)f2b(o[1]) << 16);
    out.y = (u32)f2b(o[2]) | ((u32)f2b(o[3]) << 16);
    out.z = (u32)f2b(o[4]) | ((u32)f2b(o[5]) << 16);
    out.w = (u32)f2b(o[6]) | ((u32)f2b(o[7]) << 16);
    ((uint4*)x)[tid] = out;
}

// ---------- V transpose: (b,t,h,d) bf16 -> Vt[b][h][d][t] bf16 ----------
__global__ __launch_bounds__(256) void vtrans(const u16* __restrict__ V,
                                              u16* __restrict__ Vt) {
    int bh = blockIdx.y;
    int b = bh >> 4, h = bh & 15;
    int t0 = blockIdx.x * 64;
    __shared__ u32 tile[64][133];
    int tid = threadIdx.x;
    int r = tid >> 2, seg = (tid & 3) * 32;
    const uint4* src =
        (const uint4*)(V + ((size_t)b * Tn + t0 + r) * Cn + h * HDn + seg);
#pragma unroll
    for (int i = 0; i < 4; i++) {
        uint4 u = src[i];
        u32 uu[4] = {u.x, u.y, u.z, u.w};
#pragma unroll
        for (int j = 0; j < 4; j++) {
            tile[r][seg + i * 8 + j * 2] = uu[j] & 0xffff;
            tile[r][seg + i * 8 + j * 2 + 1] = uu[j] >> 16;
        }
    }
    __syncthreads();
    int d = tid >> 1, tseg = (tid & 1) * 32;
    u16* dst = Vt + ((size_t)bh * HDn + d) * Tn + t0 + tseg;
#pragma unroll
    for (int i = 0; i < 4; i++) {
        u32 p0 = tile[tseg + i * 8 + 0][d] | (tile[tseg + i * 8 + 1][d] << 16);
        u32 p1 = tile[tseg + i * 8 + 2][d] | (tile[tseg + i * 8 + 3][d] << 16);
        u32 p2 = tile[tseg + i * 8 + 4][d] | (tile[tseg + i * 8 + 5][d] << 16);
        u32 p3 = tile[tseg + i * 8 + 6][d] | (tile[tseg + i * 8 + 7][d] << 16);
        ((uint4*)dst)[i] = make_uint4(p0, p1, p2, p3);
    }
}

// ---------- flash attention: BQ=BK=64, 4 waves, online softmax ----------
__global__ __launch_bounds__(256) void flash(const u16* __restrict__ Qb,
                                             const u16* __restrict__ Kb,
                                             const u16* __restrict__ Vt,
                                             const int* __restrict__ mask,
                                             float* __restrict__ O) {
    int qt = blockIdx.x, bh = blockIdx.y;
    int b = bh >> 4, h = bh & 15;
    int L = mask[b];
    int nk = (L + 63) >> 6;
    __shared__ u16 Qs[64 * 128];
    __shared__ u16 Ks[64 * 128];
    __shared__ u16 Vs[128 * 64];
    __shared__ u16 Ps[4][16 * 64];
    int tid = threadIdx.x, w = tid >> 6, lane = tid & 63;
    int quad = lane >> 4, l15 = lane & 15;
    {
        int r = tid >> 2, seg = (tid & 3) * 32;
        const uint4* src =
            (const uint4*)(Qb + ((size_t)b * Tn + qt * 64 + r) * Cn + h * HDn + seg);
        uint4* dst = (uint4*)(Qs + r * 128 + seg);
#pragma unroll
        for (int i = 0; i < 4; i++) dst[i] = src[i];
    }
    __syncthreads();
    v8s aq[4];
#pragma unroll
    for (int kk = 0; kk < 4; kk++)
        aq[kk] = *(const v8s*)(Qs + (w * 16 + l15) * 128 + kk * 32 + quad * 8);
    float mrow[4] = {-1e30f, -1e30f, -1e30f, -1e30f};
    float lrow[4] = {0.f, 0.f, 0.f, 0.f};
    const v4f zf = {0.f, 0.f, 0.f, 0.f};
    v4f oacc[8];
#pragma unroll
    for (int i = 0; i < 8; i++) oacc[i] = zf;
    const float scale = 0.08838834764831845f;  // 1/sqrt(128)
    for (int kt = 0; kt < nk; kt++) {
        int kb0 = kt * 64;
        {
            int r = tid >> 2, seg = (tid & 3) * 32;
            const uint4* src = (const uint4*)(Kb + ((size_t)b * Tn + kb0 + r) * Cn +
                                              h * HDn + seg);
            uint4* dst = (uint4*)(Ks + r * 128 + seg);
#pragma unroll
            for (int i = 0; i < 4; i++) dst[i] = src[i];
        }
        {
            int d = tid >> 1, seg = (tid & 1) * 32;
            const uint4* src =
                (const uint4*)(Vt + ((size_t)bh * HDn + d) * Tn + kb0 + seg);
            uint4* dst = (uint4*)(Vs + d * 64 + seg);
#pragma unroll
            for (int i = 0; i < 4; i++) dst[i] = src[i];
        }
        __syncthreads();
        v4f sacc[4];
#pragma unroll
        for (int nj = 0; nj < 4; nj++) sacc[nj] = zf;
#pragma unroll
        for (int kk = 0; kk < 4; kk++) {
#pragma unroll
            for (int nj = 0; nj < 4; nj++) {
                v8s bk =
                    *(const v8s*)(Ks + (nj * 16 + l15) * 128 + kk * 32 + quad * 8);
                sacc[nj] = __builtin_amdgcn_mfma_f32_16x16x32_bf16(aq[kk], bk,
                                                                   sacc[nj], 0, 0, 0);
            }
        }
        float sv[4][4];
#pragma unroll
        for (int nj = 0; nj < 4; nj++) {
            bool valid = (kb0 + nj * 16 + l15) < L;
#pragma unroll
            for (int r2 = 0; r2 < 4; r2++)
                sv[nj][r2] = valid ? sacc[nj][r2] * scale : -1e9f;
        }
        float alpha[4];
#pragma unroll
        for (int r2 = 0; r2 < 4; r2++) {
            float mm = fmaxf(fmaxf(sv[0][r2], sv[1][r2]), fmaxf(sv[2][r2], sv[3][r2]));
#pragma unroll
            for (int o = 8; o; o >>= 1) mm = fmaxf(mm, __shfl_xor(mm, o));
            float mn = fmaxf(mrow[r2], mm);
            alpha[r2] = __expf(mrow[r2] - mn);
            mrow[r2] = mn;
        }
        float sum[4] = {0.f, 0.f, 0.f, 0.f};
        u16 pb[4][4];
#pragma unroll
        for (int nj = 0; nj < 4; nj++)
#pragma unroll
            for (int r2 = 0; r2 < 4; r2++) {
                float p = __expf(sv[nj][r2] - mrow[r2]);
                sum[r2] += p;
                pb[nj][r2] = f2b(p);
            }
#pragma unroll
        for (int r2 = 0; r2 < 4; r2++) {
            float s2 = sum[r2];
#pragma unroll
            for (int o = 8; o; o >>= 1) s2 += __shfl_xor(s2, o);
            lrow[r2] = lrow[r2] * alpha[r2] + s2;
        }
#pragma unroll
        for (int nj2 = 0; nj2 < 8; nj2++)
#pragma unroll
            for (int r2 = 0; r2 < 4; r2++) oacc[nj2][r2] *= alpha[r2];
        u16* pw = &Ps[w][0];
#pragma unroll
        for (int nj = 0; nj < 4; nj++)
#pragma unroll
            for (int r2 = 0; r2 < 4; r2++)
                pw[(quad * 4 + r2) * 64 + nj * 16 + l15] = pb[nj][r2];
        asm volatile("s_waitcnt lgkmcnt(0)" ::: "memory");
#pragma unroll
        for (int kk2 = 0; kk2 < 2; kk2++) {
            v8s ap = *(const v8s*)(pw + l15 * 64 + kk2 * 32 + quad * 8);
#pragma unroll
            for (int nj2 = 0; nj2 < 8; nj2++) {
                v8s bv =
                    *(const v8s*)(Vs + (nj2 * 16 + l15) * 64 + kk2 * 32 + quad * 8);
                oacc[nj2] = __builtin_amdgcn_mfma_f32_16x16x32_bf16(ap, bv, oacc[nj2],
                                                                    0, 0, 0);
            }
        }
        __syncthreads();
    }
    float inv4[4];
#pragma unroll
    for (int r2 = 0; r2 < 4; r2++) inv4[r2] = 1.f / lrow[r2];
#pragma unroll
    for (int nj2 = 0; nj2 < 8; nj2++) {
        int d = h * HDn + nj2 * 16 + l15;
#pragma unroll
        for (int r2 = 0; r2 < 4; r2++) {
            int q = qt * 64 + w * 16 + quad * 4 + r2;
            O[((size_t)b * Tn + q) * Cn + d] = oacc[nj2][r2] * inv4[r2];
        }
    }
}

extern "C" void kernel_launch(void* const* d_in, const int* in_sizes, int n_in,
                              void* d_out, int out_size, void* d_ws,
                              size_t ws_size, hipStream_t stream) {
    // All float tensors are fp32 (per the reference). Output is fp32.
    const float* hidden = (const float*)d_in[0];
    const int* mask = (const int*)d_in[1];
    const float* wq = (const float*)d_in[2];
    const float* wk = (const float*)d_in[3];
    const float* wv = (const float*)d_in[4];
    const float* wo = (const float*)d_in[5];
    const float* qg = (const float*)d_in[6];
    const float* kg = (const float*)d_in[7];
    const float* cs = (const float*)d_in[8];
    const float* sn = (const float*)d_in[9];

    char* ws = (char*)d_ws;
    int8_t* wq8 = (int8_t*)(ws);                 // 4 x 4 MiB (q,k,v,o)
    float* sw = (float*)(ws + 16777216);         // 4 x 2048 fp32
    int8_t* xq8 = (int8_t*)(ws + 16809984);      // 8 MiB (reused for O-quant)
    float* sx = (float*)(ws + 25198592);         // 4096 fp32
    float* so = (float*)(ws + 25214976);         // 4096 fp32
    u16* qb = (u16*)(ws + 25231360);             // Q bf16 (B,T,C)
    u16* kb = (u16*)(ws + 42008576);             // K bf16
    u16* vb = (u16*)(ws + 58785792);             // V bf16
    u16* vt = (u16*)(ws + 75563008);             // V^T bf16 (B,H,HD,T)
    float* Obuf = (float*)(ws + 92340224);       // O fp32 (B,T,C)
    // total ws use: 125,894,656 bytes

    quant_rows<<<2048, 256, 0, stream>>>(wq, wq8, sw);
    quant_rows<<<2048, 256, 0, stream>>>(wk, wq8 + 4194304, sw + 2048);
    quant_rows<<<2048, 256, 0, stream>>>(wv, wq8 + 8388608, sw + 4096);
    quant_rows<<<2048, 256, 0, stream>>>(wo, wq8 + 12582912, sw + 6144);
    quant_rows<<<4096, 256, 0, stream>>>(hidden, xq8, sx);

    gemm_i8<<<dim3(32, 16, 3), 256, 0, stream>>>(xq8, wq8, sx, sw, (void*)qb,
                                                 4194304LL, 2048LL, 8388608LL, 0);

    norm_rope<<<4096, 256, 0, stream>>>(qb, qg, cs, sn);
    norm_rope<<<4096, 256, 0, stream>>>(kb, kg, cs, sn);
    vtrans<<<dim3(32, 32), 256, 0, stream>>>(vb, vt);

    flash<<<dim3(32, 32), 256, 0, stream>>>(qb, kb, vt, mask, Obuf);

    quant_rows<<<4096, 256, 0, stream>>>(Obuf, xq8, so);
    gemm_i8<<<dim3(32, 16, 1), 256, 0, stream>>>(xq8, wq8 + 12582912, so,
                                                 sw + 6144, d_out, 0LL, 0LL,
                                                 0LL, 1);
}

// Round 4
// 383.573 us; speedup vs baseline: 1.2510x; 1.2510x over previous
//
#include <hip/hip_runtime.h>
#include <stdint.h>

typedef unsigned short u16;
typedef unsigned int u32;
typedef int v4i __attribute__((ext_vector_type(4)));
typedef float v4f __attribute__((ext_vector_type(4)));
typedef short v8s __attribute__((ext_vector_type(8)));

#define Bn 2
#define Tn 2048
#define Cn 2048
#define Hn 16
#define HDn 128

__device__ __forceinline__ float b2f(u16 u) {
    u32 x = ((u32)u) << 16;
    float f;
    __builtin_memcpy(&f, &x, 4);
    return f;
}
__device__ __forceinline__ u16 f2b(float f) {
    u32 x;
    __builtin_memcpy(&x, &f, 4);
    u32 r = (x + 0x7fffu + ((x >> 16) & 1u)) >> 16;
    return (u16)r;
}

__device__ __forceinline__ void async16(const void* g, void* l) {
    __builtin_amdgcn_global_load_lds(
        (const __attribute__((address_space(1))) u32*)g,
        (__attribute__((address_space(3))) u32*)l, 16, 0, 0);
}

// ---------- row quantization: X[R][2048] fp32 -> int8 + scale ----------
__global__ __launch_bounds__(256) void quant_rows(const float* __restrict__ X,
                                                  int8_t* __restrict__ Q,
                                                  float* __restrict__ S) {
    int r = blockIdx.x;
    const float* x = X + (size_t)r * Cn;
    int tid = threadIdx.x;
    float4 v0 = ((const float4*)x)[tid * 2];
    float4 v1 = ((const float4*)x)[tid * 2 + 1];
    float a[8] = {v0.x, v0.y, v0.z, v0.w, v1.x, v1.y, v1.z, v1.w};
    float m = 0.f;
#pragma unroll
    for (int i = 0; i < 8; i++) m = fmaxf(m, fabsf(a[i]));
#pragma unroll
    for (int o = 32; o; o >>= 1) m = fmaxf(m, __shfl_xor(m, o));
    __shared__ float sm[4];
    if ((tid & 63) == 0) sm[tid >> 6] = m;
    __syncthreads();
    m = fmaxf(fmaxf(sm[0], sm[1]), fmaxf(sm[2], sm[3]));
    float s = m * (1.0f / 127.0f) + 1e-8f;
    if (tid == 0) S[r] = s;
    u32 lo = 0, hi = 0;
#pragma unroll
    for (int i = 0; i < 8; i++) {
        float q = rintf(fminf(127.f, fmaxf(-127.f, a[i] / s)));
        int qi = (int)q;
        u32 byte = (u32)(qi & 0xff);
        if (i < 4) lo |= byte << (8 * i);
        else hi |= byte << (8 * (i - 4));
    }
    u32* qp = (u32*)(Q + (size_t)r * Cn);
    qp[tid * 2] = lo;
    qp[tid * 2 + 1] = hi;
}

// ---------- int8 GEMM: C[m][n] = (A[m][:] . B[n][:]) * sA[m]*sB[n]
// 128x128 tile, BK=64, 4 waves. XOR-swizzled LDS k-groups (bank-conflict fix:
// row stride 64B == 16 banks, so unswizzled reads are 8-way conflicted).
__global__ __launch_bounds__(256) void gemm_i8(
    const int8_t* __restrict__ A, const int8_t* __restrict__ Bw,
    const float* __restrict__ sA, const float* __restrict__ sB,
    void* __restrict__ Co, long long bStride, long long sbStride,
    long long cStride, int fp32out) {
    int z = blockIdx.z;
    Bw += (size_t)z * bStride;
    sB += (size_t)z * sbStride;
    const int K = 2048, N = 2048;
    __shared__ int8_t As[128 * 64];
    __shared__ int8_t Bs[128 * 64];
    int m0 = blockIdx.x * 128, n0 = blockIdx.y * 128;
    int tid = threadIdx.x, w = tid >> 6, lane = tid & 63;
    int quad = lane >> 4, l15 = lane & 15;
    int wy = w >> 1, wx = w & 1;
    const v4i zi = {0, 0, 0, 0};
    v4i acc[4][4];
#pragma unroll
    for (int i = 0; i < 4; i++)
#pragma unroll
        for (int j = 0; j < 4; j++) acc[i][j] = zi;
    int lrow = lane >> 2;  // 0..15
    int slot = lane & 3;   // physical 16B slot within the 64B row
    int srow = w * 32 + lrow;
    int klog = ((slot ^ (lrow & 3)) * 16);  // logical k-group staged here
    const int8_t* ga = A + (size_t)(m0 + srow) * K + klog;
    const int8_t* gb = Bw + (size_t)(n0 + srow) * K + klog;
    int8_t* la = &As[srow * 64 + slot * 16];  // == As + w*2048 + lane*16
    int8_t* lb = &Bs[srow * 64 + slot * 16];
    for (int k0 = 0; k0 < K; k0 += 64) {
        async16(ga + k0, la);
        async16(ga + k0 + (size_t)16 * K, la + 16 * 64);
        async16(gb + k0, lb);
        async16(gb + k0 + (size_t)16 * K, lb + 16 * 64);
        __syncthreads();
        int swz = (quad ^ (l15 & 3)) * 16;  // physical slot holding k-group `quad`
        v4i af[4], bf4[4];
#pragma unroll
        for (int i = 0; i < 4; i++)
            af[i] = *(const v4i*)&As[(wy * 64 + i * 16 + l15) * 64 + swz];
#pragma unroll
        for (int j = 0; j < 4; j++)
            bf4[j] = *(const v4i*)&Bs[(wx * 64 + j * 16 + l15) * 64 + swz];
#pragma unroll
        for (int i = 0; i < 4; i++)
#pragma unroll
            for (int j = 0; j < 4; j++)
                acc[i][j] = __builtin_amdgcn_mfma_i32_16x16x64_i8(
                    af[i], bf4[j], acc[i][j], 0, 0, 0);
        __syncthreads();
    }
#pragma unroll
    for (int i = 0; i < 4; i++) {
        int mb = m0 + wy * 64 + i * 16 + quad * 4;
        float s0 = sA[mb], s1 = sA[mb + 1], s2 = sA[mb + 2], s3 = sA[mb + 3];
#pragma unroll
        for (int j = 0; j < 4; j++) {
            int n = n0 + wx * 64 + j * 16 + l15;
            float sb = sB[n];
            if (fp32out) {
                float* cp = (float*)Co + (size_t)cStride * z + (size_t)mb * N + n;
                cp[0] = (float)acc[i][j][0] * s0 * sb;
                cp[N] = (float)acc[i][j][1] * s1 * sb;
                cp[2 * N] = (float)acc[i][j][2] * s2 * sb;
                cp[3 * N] = (float)acc[i][j][3] * s3 * sb;
            } else {
                u16* cp = (u16*)Co + (size_t)cStride * z + (size_t)mb * N + n;
                cp[0] = f2b((float)acc[i][j][0] * s0 * sb);
                cp[N] = f2b((float)acc[i][j][1] * s1 * sb);
                cp[2 * N] = f2b((float)acc[i][j][2] * s2 * sb);
                cp[3 * N] = f2b((float)acc[i][j][3] * s3 * sb);
            }
        }
    }
}

// ---------- fused RMSNorm (full 2048-dim row) + interleaved RoPE, in-place bf16
__global__ __launch_bounds__(256) void norm_rope(u16* __restrict__ X,
                                                 const float* __restrict__ g,
                                                 const float* __restrict__ cs,
                                                 const float* __restrict__ sn) {
    int row = blockIdx.x;
    int t = row & (Tn - 1);
    u16* x = X + (size_t)row * Cn;
    int tid = threadIdx.x;
    uint4 raw = ((const uint4*)x)[tid];
    u16 us[8];
    us[0] = raw.x & 0xffff; us[1] = raw.x >> 16;
    us[2] = raw.y & 0xffff; us[3] = raw.y >> 16;
    us[4] = raw.z & 0xffff; us[5] = raw.z >> 16;
    us[6] = raw.w & 0xffff; us[7] = raw.w >> 16;
    float v[8];
#pragma unroll
    for (int i = 0; i < 8; i++) v[i] = b2f(us[i]);
    float ss = 0.f;
#pragma unroll
    for (int i = 0; i < 8; i++) ss += v[i] * v[i];
#pragma unroll
    for (int o = 32; o; o >>= 1) ss += __shfl_xor(ss, o);
    __shared__ float sm[4];
    if ((tid & 63) == 0) sm[tid >> 6] = ss;
    __syncthreads();
    ss = sm[0] + sm[1] + sm[2] + sm[3];
    float r = rsqrtf(ss * (1.f / 2048.f) + 1e-6f);
    float4 g0 = ((const float4*)g)[tid * 2];
    float4 g1 = ((const float4*)g)[tid * 2 + 1];
    float n[8];
    n[0] = v[0] * r * g0.x; n[1] = v[1] * r * g0.y;
    n[2] = v[2] * r * g0.z; n[3] = v[3] * r * g0.w;
    n[4] = v[4] * r * g1.x; n[5] = v[5] * r * g1.y;
    n[6] = v[6] * r * g1.z; n[7] = v[7] * r * g1.w;
    int pi = (tid & 15) * 4;  // pair index within head, 4 consecutive pairs
    float4 c4 = *(const float4*)(cs + t * 64 + pi);
    float4 s4 = *(const float4*)(sn + t * 64 + pi);
    float o[8];
    o[0] = n[0] * c4.x - n[1] * s4.x; o[1] = n[0] * s4.x + n[1] * c4.x;
    o[2] = n[2] * c4.y - n[3] * s4.y; o[3] = n[2] * s4.y + n[3] * c4.y;
    o[4] = n[4] * c4.z - n[5] * s4.z; o[5] = n[4] * s4.z + n[5] * c4.z;
    o[6] = n[6] * c4.w - n[7] * s4.w; o[7] = n[6] * s4.w + n[7] * c4.w;
    uint4 out;
    out.x = (u32)f2b(o[0]) | ((u32)f2b(o[1]) << 16);
    out.y = (u32)f2b(o[2]) | ((u32)f2b(o[3]) << 16);
    out.z = (u32)f2b(o[4]) | ((u32)f2b(o[5]) << 16);
    out.w = (u32)f2b(o[6]) | ((u32)f2b(o[7]) << 16);
    ((uint4*)x)[tid] = out;
}

// ---------- V transpose: (b,t,h,d) bf16 -> Vt[b][h][d][t] bf16 ----------
__global__ __launch_bounds__(256) void vtrans(const u16* __restrict__ V,
                                              u16* __restrict__ Vt) {
    int bh = blockIdx.y;
    int b = bh >> 4, h = bh & 15;
    int t0 = blockIdx.x * 64;
    __shared__ u32 tile[64][133];
    int tid = threadIdx.x;
    int r = tid >> 2, seg = (tid & 3) * 32;
    const uint4* src =
        (const uint4*)(V + ((size_t)b * Tn + t0 + r) * Cn + h * HDn + seg);
#pragma unroll
    for (int i = 0; i < 4; i++) {
        uint4 u = src[i];
        u32 uu[4] = {u.x, u.y, u.z, u.w};
#pragma unroll
        for (int j = 0; j < 4; j++) {
            tile[r][seg + i * 8 + j * 2] = uu[j] & 0xffff;
            tile[r][seg + i * 8 + j * 2 + 1] = uu[j] >> 16;
        }
    }
    __syncthreads();
    int d = tid >> 1, tseg = (tid & 1) * 32;
    u16* dst = Vt + ((size_t)bh * HDn + d) * Tn + t0 + tseg;
#pragma unroll
    for (int i = 0; i < 4; i++) {
        u32 p0 = tile[tseg + i * 8 + 0][d] | (tile[tseg + i * 8 + 1][d] << 16);
        u32 p1 = tile[tseg + i * 8 + 2][d] | (tile[tseg + i * 8 + 3][d] << 16);
        u32 p2 = tile[tseg + i * 8 + 4][d] | (tile[tseg + i * 8 + 5][d] << 16);
        u32 p3 = tile[tseg + i * 8 + 6][d] | (tile[tseg + i * 8 + 7][d] << 16);
        ((uint4*)dst)[i] = make_uint4(p0, p1, p2, p3);
    }
}

// ---------- flash attention: BQ=BK=64, 4 waves, online softmax ----------
// LDS rows padded to odd multiples of 16B -> 2-way max bank aliasing (free).
#define KS_S 136  // u16: 128 + 8 pad
#define VS_S 72   // u16: 64 + 8 pad
#define PS_S 72   // u16: 64 + 8 pad
__global__ __launch_bounds__(256) void flash(const u16* __restrict__ Qb,
                                             const u16* __restrict__ Kb,
                                             const u16* __restrict__ Vt,
                                             const int* __restrict__ mask,
                                             float* __restrict__ O) {
    int qt = blockIdx.x, bh = blockIdx.y;
    int b = bh >> 4, h = bh & 15;
    int L = mask[b];
    int nk = (L + 63) >> 6;
    __shared__ u16 Ks[64 * KS_S];
    __shared__ u16 Vs[128 * VS_S];
    __shared__ u16 Ps[4][16 * PS_S];
    int tid = threadIdx.x, w = tid >> 6, lane = tid & 63;
    int quad = lane >> 4, l15 = lane & 15;
    // Q A-fragments direct from global (each row read once, by its own block)
    const u16* qrow =
        Qb + ((size_t)b * Tn + qt * 64 + w * 16 + l15) * Cn + h * HDn;
    v8s aq[4];
#pragma unroll
    for (int kk = 0; kk < 4; kk++)
        aq[kk] = *(const v8s*)(qrow + kk * 32 + quad * 8);
    float mrow[4] = {-1e30f, -1e30f, -1e30f, -1e30f};
    float lrow[4] = {0.f, 0.f, 0.f, 0.f};
    const v4f zf = {0.f, 0.f, 0.f, 0.f};
    v4f oacc[8];
#pragma unroll
    for (int i = 0; i < 8; i++) oacc[i] = zf;
    const float scale = 0.08838834764831845f;  // 1/sqrt(128)
    for (int kt = 0; kt < nk; kt++) {
        int kb0 = kt * 64;
        {
            int r = tid >> 2, seg = (tid & 3) * 32;
            const uint4* src = (const uint4*)(Kb + ((size_t)b * Tn + kb0 + r) * Cn +
                                              h * HDn + seg);
            uint4* dst = (uint4*)(Ks + r * KS_S + seg);
#pragma unroll
            for (int i = 0; i < 4; i++) dst[i] = src[i];
        }
        {
            int d = tid >> 1, seg = (tid & 1) * 32;
            const uint4* src =
                (const uint4*)(Vt + ((size_t)bh * HDn + d) * Tn + kb0 + seg);
            uint4* dst = (uint4*)(Vs + d * VS_S + seg);
#pragma unroll
            for (int i = 0; i < 4; i++) dst[i] = src[i];
        }
        __syncthreads();
        v4f sacc[4];
#pragma unroll
        for (int nj = 0; nj < 4; nj++) sacc[nj] = zf;
#pragma unroll
        for (int kk = 0; kk < 4; kk++) {
#pragma unroll
            for (int nj = 0; nj < 4; nj++) {
                v8s bk =
                    *(const v8s*)(Ks + (nj * 16 + l15) * KS_S + kk * 32 + quad * 8);
                sacc[nj] = __builtin_amdgcn_mfma_f32_16x16x32_bf16(aq[kk], bk,
                                                                   sacc[nj], 0, 0, 0);
            }
        }
        float sv[4][4];
#pragma unroll
        for (int nj = 0; nj < 4; nj++) {
            bool valid = (kb0 + nj * 16 + l15) < L;
#pragma unroll
            for (int r2 = 0; r2 < 4; r2++)
                sv[nj][r2] = valid ? sacc[nj][r2] * scale : -1e9f;
        }
        float alpha[4];
#pragma unroll
        for (int r2 = 0; r2 < 4; r2++) {
            float mm = fmaxf(fmaxf(sv[0][r2], sv[1][r2]), fmaxf(sv[2][r2], sv[3][r2]));
#pragma unroll
            for (int o = 8; o; o >>= 1) mm = fmaxf(mm, __shfl_xor(mm, o));
            float mn = fmaxf(mrow[r2], mm);
            alpha[r2] = __expf(mrow[r2] - mn);
            mrow[r2] = mn;
        }
        float sum[4] = {0.f, 0.f, 0.f, 0.f};
        u16 pb[4][4];
#pragma unroll
        for (int nj = 0; nj < 4; nj++)
#pragma unroll
            for (int r2 = 0; r2 < 4; r2++) {
                float p = __expf(sv[nj][r2] - mrow[r2]);
                sum[r2] += p;
                pb[nj][r2] = f2b(p);
            }
#pragma unroll
        for (int r2 = 0; r2 < 4; r2++) {
            float s2 = sum[r2];
#pragma unroll
            for (int o = 8; o; o >>= 1) s2 += __shfl_xor(s2, o);
            lrow[r2] = lrow[r2] * alpha[r2] + s2;
        }
#pragma unroll
        for (int nj2 = 0; nj2 < 8; nj2++)
#pragma unroll
            for (int r2 = 0; r2 < 4; r2++) oacc[nj2][r2] *= alpha[r2];
        u16* pw = &Ps[w][0];
#pragma unroll
        for (int nj = 0; nj < 4; nj++)
#pragma unroll
            for (int r2 = 0; r2 < 4; r2++)
                pw[(quad * 4 + r2) * PS_S + nj * 16 + l15] = pb[nj][r2];
        asm volatile("s_waitcnt lgkmcnt(0)" ::: "memory");
#pragma unroll
        for (int kk2 = 0; kk2 < 2; kk2++) {
            v8s ap = *(const v8s*)(pw + l15 * PS_S + kk2 * 32 + quad * 8);
#pragma unroll
            for (int nj2 = 0; nj2 < 8; nj2++) {
                v8s bv =
                    *(const v8s*)(Vs + (nj2 * 16 + l15) * VS_S + kk2 * 32 + quad * 8);
                oacc[nj2] = __builtin_amdgcn_mfma_f32_16x16x32_bf16(ap, bv, oacc[nj2],
                                                                    0, 0, 0);
            }
        }
        __syncthreads();
    }
    float inv4[4];
#pragma unroll
    for (int r2 = 0; r2 < 4; r2++) inv4[r2] = 1.f / lrow[r2];
#pragma unroll
    for (int nj2 = 0; nj2 < 8; nj2++) {
        int d = h * HDn + nj2 * 16 + l15;
#pragma unroll
        for (int r2 = 0; r2 < 4; r2++) {
            int q = qt * 64 + w * 16 + quad * 4 + r2;
            O[((size_t)b * Tn + q) * Cn + d] = oacc[nj2][r2] * inv4[r2];
        }
    }
}

extern "C" void kernel_launch(void* const* d_in, const int* in_sizes, int n_in,
                              void* d_out, int out_size, void* d_ws,
                              size_t ws_size, hipStream_t stream) {
    const float* hidden = (const float*)d_in[0];
    const int* mask = (const int*)d_in[1];
    const float* wq = (const float*)d_in[2];
    const float* wk = (const float*)d_in[3];
    const float* wv = (const float*)d_in[4];
    const float* wo = (const float*)d_in[5];
    const float* qg = (const float*)d_in[6];
    const float* kg = (const float*)d_in[7];
    const float* cs = (const float*)d_in[8];
    const float* sn = (const float*)d_in[9];

    char* ws = (char*)d_ws;
    int8_t* wq8 = (int8_t*)(ws);                 // 4 x 4 MiB (q,k,v,o)
    float* sw = (float*)(ws + 16777216);         // 4 x 2048 fp32
    int8_t* xq8 = (int8_t*)(ws + 16809984);      // 8 MiB (reused for O-quant)
    float* sx = (float*)(ws + 25198592);         // 4096 fp32
    float* so = (float*)(ws + 25214976);         // 4096 fp32
    u16* qb = (u16*)(ws + 25231360);             // Q bf16 (B,T,C)
    u16* kb = (u16*)(ws + 42008576);             // K bf16
    u16* vb = (u16*)(ws + 58785792);             // V bf16
    u16* vt = (u16*)(ws + 75563008);             // V^T bf16 (B,H,HD,T)
    float* Obuf = (float*)(ws + 92340224);       // O fp32 (B,T,C)
    // total ws use: 125,894,656 bytes

    quant_rows<<<2048, 256, 0, stream>>>(wq, wq8, sw);
    quant_rows<<<2048, 256, 0, stream>>>(wk, wq8 + 4194304, sw + 2048);
    quant_rows<<<2048, 256, 0, stream>>>(wv, wq8 + 8388608, sw + 4096);
    quant_rows<<<2048, 256, 0, stream>>>(wo, wq8 + 12582912, sw + 6144);
    quant_rows<<<4096, 256, 0, stream>>>(hidden, xq8, sx);

    gemm_i8<<<dim3(32, 16, 3), 256, 0, stream>>>(xq8, wq8, sx, sw, (void*)qb,
                                                 4194304LL, 2048LL, 8388608LL, 0);

    norm_rope<<<4096, 256, 0, stream>>>(qb, qg, cs, sn);
    norm_rope<<<4096, 256, 0, stream>>>(kb, kg, cs, sn);
    vtrans<<<dim3(32, 32), 256, 0, stream>>>(vb, vt);

    flash<<<dim3(32, 32), 256, 0, stream>>>(qb, kb, vt, mask, Obuf);

    quant_rows<<<4096, 256, 0, stream>>>(Obuf, xq8, so);
    gemm_i8<<<dim3(32, 16, 1), 256, 0, stream>>>(xq8, wq8 + 12582912, so,
                                                 sw + 6144, d_out, 0LL, 0LL,
                                                 0LL, 1);
}

// Round 5
// 355.955 us; speedup vs baseline: 1.3480x; 1.0776x over previous
//
#include <hip/hip_runtime.h>
#include <stdint.h>

typedef unsigned short u16;
typedef unsigned int u32;
typedef int v4i __attribute__((ext_vector_type(4)));
typedef float v4f __attribute__((ext_vector_type(4)));
typedef short v8s __attribute__((ext_vector_type(8)));

#define Bn 2
#define Tn 2048
#define Cn 2048
#define Hn 16
#define HDn 128

__device__ __forceinline__ float b2f(u16 u) {
    u32 x = ((u32)u) << 16;
    float f;
    __builtin_memcpy(&f, &x, 4);
    return f;
}
__device__ __forceinline__ u16 f2b(float f) {
    u32 x;
    __builtin_memcpy(&x, &f, 4);
    u32 r = (x + 0x7fffu + ((x >> 16) & 1u)) >> 16;
    return (u16)r;
}

__device__ __forceinline__ void async16(const void* g, void* l) {
    __builtin_amdgcn_global_load_lds(
        (const __attribute__((address_space(1))) u32*)g,
        (__attribute__((address_space(3))) u32*)l, 16, 0, 0);
}

// ---------- fused row quantization: 4 weight matrices (2048 rows each) +
// hidden (4096 rows), all fp32 -> int8 rows + scales, one launch ----------
__global__ __launch_bounds__(256) void quant_all(
    const float* __restrict__ w0, const float* __restrict__ w1,
    const float* __restrict__ w2, const float* __restrict__ w3,
    const float* __restrict__ hid, int8_t* __restrict__ Q,
    float* __restrict__ S) {
    int r = blockIdx.x;
    const float* src;
    int ro;
    if (r < 2048) { src = w0; ro = r; }
    else if (r < 4096) { src = w1; ro = r - 2048; }
    else if (r < 6144) { src = w2; ro = r - 4096; }
    else if (r < 8192) { src = w3; ro = r - 6144; }
    else { src = hid; ro = r - 8192; }
    const float* x = src + (size_t)ro * Cn;
    int tid = threadIdx.x;
    float4 v0 = ((const float4*)x)[tid * 2];
    float4 v1 = ((const float4*)x)[tid * 2 + 1];
    float a[8] = {v0.x, v0.y, v0.z, v0.w, v1.x, v1.y, v1.z, v1.w};
    float m = 0.f;
#pragma unroll
    for (int i = 0; i < 8; i++) m = fmaxf(m, fabsf(a[i]));
#pragma unroll
    for (int o = 32; o; o >>= 1) m = fmaxf(m, __shfl_xor(m, o));
    __shared__ float sm[4];
    if ((tid & 63) == 0) sm[tid >> 6] = m;
    __syncthreads();
    m = fmaxf(fmaxf(sm[0], sm[1]), fmaxf(sm[2], sm[3]));
    float s = m * (1.0f / 127.0f) + 1e-8f;
    if (tid == 0) S[r] = s;
    u32 lo = 0, hi = 0;
#pragma unroll
    for (int i = 0; i < 8; i++) {
        float q = rintf(fminf(127.f, fmaxf(-127.f, a[i] / s)));
        int qi = (int)q;
        u32 byte = (u32)(qi & 0xff);
        if (i < 4) lo |= byte << (8 * i);
        else hi |= byte << (8 * (i - 4));
    }
    u32* qp = (u32*)(Q + (size_t)r * Cn);
    qp[tid * 2] = lo;
    qp[tid * 2 + 1] = hi;
}

// ---------- row quantization (fp32, used for attention output O) ----------
__global__ __launch_bounds__(256) void quant_rows(const float* __restrict__ X,
                                                  int8_t* __restrict__ Q,
                                                  float* __restrict__ S) {
    int r = blockIdx.x;
    const float* x = X + (size_t)r * Cn;
    int tid = threadIdx.x;
    float4 v0 = ((const float4*)x)[tid * 2];
    float4 v1 = ((const float4*)x)[tid * 2 + 1];
    float a[8] = {v0.x, v0.y, v0.z, v0.w, v1.x, v1.y, v1.z, v1.w};
    float m = 0.f;
#pragma unroll
    for (int i = 0; i < 8; i++) m = fmaxf(m, fabsf(a[i]));
#pragma unroll
    for (int o = 32; o; o >>= 1) m = fmaxf(m, __shfl_xor(m, o));
    __shared__ float sm[4];
    if ((tid & 63) == 0) sm[tid >> 6] = m;
    __syncthreads();
    m = fmaxf(fmaxf(sm[0], sm[1]), fmaxf(sm[2], sm[3]));
    float s = m * (1.0f / 127.0f) + 1e-8f;
    if (tid == 0) S[r] = s;
    u32 lo = 0, hi = 0;
#pragma unroll
    for (int i = 0; i < 8; i++) {
        float q = rintf(fminf(127.f, fmaxf(-127.f, a[i] / s)));
        int qi = (int)q;
        u32 byte = (u32)(qi & 0xff);
        if (i < 4) lo |= byte << (8 * i);
        else hi |= byte << (8 * (i - 4));
    }
    u32* qp = (u32*)(Q + (size_t)r * Cn);
    qp[tid * 2] = lo;
    qp[tid * 2 + 1] = hi;
}

// ---------- int8 GEMM: C[m][n] = (A[m][:] . B[n][:]) * sA[m]*sB[n]
// 128x128 tile, BK=64, 4 waves, XOR-swizzled LDS k-groups.
__global__ __launch_bounds__(256) void gemm_i8(
    const int8_t* __restrict__ A, const int8_t* __restrict__ Bw,
    const float* __restrict__ sA, const float* __restrict__ sB,
    void* __restrict__ Co, long long bStride, long long sbStride,
    long long cStride, int fp32out) {
    int z = blockIdx.z;
    Bw += (size_t)z * bStride;
    sB += (size_t)z * sbStride;
    const int K = 2048, N = 2048;
    __shared__ int8_t As[128 * 64];
    __shared__ int8_t Bs[128 * 64];
    int m0 = blockIdx.x * 128, n0 = blockIdx.y * 128;
    int tid = threadIdx.x, w = tid >> 6, lane = tid & 63;
    int quad = lane >> 4, l15 = lane & 15;
    int wy = w >> 1, wx = w & 1;
    const v4i zi = {0, 0, 0, 0};
    v4i acc[4][4];
#pragma unroll
    for (int i = 0; i < 4; i++)
#pragma unroll
        for (int j = 0; j < 4; j++) acc[i][j] = zi;
    int lrow = lane >> 2;
    int slot = lane & 3;
    int srow = w * 32 + lrow;
    int klog = ((slot ^ (lrow & 3)) * 16);
    const int8_t* ga = A + (size_t)(m0 + srow) * K + klog;
    const int8_t* gb = Bw + (size_t)(n0 + srow) * K + klog;
    int8_t* la = &As[srow * 64 + slot * 16];
    int8_t* lb = &Bs[srow * 64 + slot * 16];
    for (int k0 = 0; k0 < K; k0 += 64) {
        async16(ga + k0, la);
        async16(ga + k0 + (size_t)16 * K, la + 16 * 64);
        async16(gb + k0, lb);
        async16(gb + k0 + (size_t)16 * K, lb + 16 * 64);
        __syncthreads();
        int swz = (quad ^ (l15 & 3)) * 16;
        v4i af[4], bf4[4];
#pragma unroll
        for (int i = 0; i < 4; i++)
            af[i] = *(const v4i*)&As[(wy * 64 + i * 16 + l15) * 64 + swz];
#pragma unroll
        for (int j = 0; j < 4; j++)
            bf4[j] = *(const v4i*)&Bs[(wx * 64 + j * 16 + l15) * 64 + swz];
#pragma unroll
        for (int i = 0; i < 4; i++)
#pragma unroll
            for (int j = 0; j < 4; j++)
                acc[i][j] = __builtin_amdgcn_mfma_i32_16x16x64_i8(
                    af[i], bf4[j], acc[i][j], 0, 0, 0);
        __syncthreads();
    }
#pragma unroll
    for (int i = 0; i < 4; i++) {
        int mb = m0 + wy * 64 + i * 16 + quad * 4;
        float s0 = sA[mb], s1 = sA[mb + 1], s2 = sA[mb + 2], s3 = sA[mb + 3];
#pragma unroll
        for (int j = 0; j < 4; j++) {
            int n = n0 + wx * 64 + j * 16 + l15;
            float sb = sB[n];
            if (fp32out) {
                float* cp = (float*)Co + (size_t)cStride * z + (size_t)mb * N + n;
                cp[0] = (float)acc[i][j][0] * s0 * sb;
                cp[N] = (float)acc[i][j][1] * s1 * sb;
                cp[2 * N] = (float)acc[i][j][2] * s2 * sb;
                cp[3 * N] = (float)acc[i][j][3] * s3 * sb;
            } else {
                u16* cp = (u16*)Co + (size_t)cStride * z + (size_t)mb * N + n;
                cp[0] = f2b((float)acc[i][j][0] * s0 * sb);
                cp[N] = f2b((float)acc[i][j][1] * s1 * sb);
                cp[2 * N] = f2b((float)acc[i][j][2] * s2 * sb);
                cp[3 * N] = f2b((float)acc[i][j][3] * s3 * sb);
            }
        }
    }
}

// ---------- fused RMSNorm + RoPE for Q and K in one launch, in-place bf16.
// Q half gets 1/sqrt(HD) folded in (linear; attention is Q's only consumer).
__global__ __launch_bounds__(256) void norm_rope2(u16* __restrict__ Qb,
                                                  u16* __restrict__ Kb,
                                                  const float* __restrict__ qg,
                                                  const float* __restrict__ kg,
                                                  const float* __restrict__ cs,
                                                  const float* __restrict__ sn) {
    int row = blockIdx.x;
    int isq = row < 4096;
    row &= 4095;
    u16* x = (isq ? Qb : Kb) + (size_t)row * Cn;
    const float* g = isq ? qg : kg;
    float ps = isq ? 0.08838834764831845f : 1.0f;  // 1/sqrt(128) folded into Q
    int t = row & (Tn - 1);
    int tid = threadIdx.x;
    uint4 raw = ((const uint4*)x)[tid];
    u16 us[8];
    us[0] = raw.x & 0xffff; us[1] = raw.x >> 16;
    us[2] = raw.y & 0xffff; us[3] = raw.y >> 16;
    us[4] = raw.z & 0xffff; us[5] = raw.z >> 16;
    us[6] = raw.w & 0xffff; us[7] = raw.w >> 16;
    float v[8];
#pragma unroll
    for (int i = 0; i < 8; i++) v[i] = b2f(us[i]);
    float ss = 0.f;
#pragma unroll
    for (int i = 0; i < 8; i++) ss += v[i] * v[i];
#pragma unroll
    for (int o = 32; o; o >>= 1) ss += __shfl_xor(ss, o);
    __shared__ float sm[4];
    if ((tid & 63) == 0) sm[tid >> 6] = ss;
    __syncthreads();
    ss = sm[0] + sm[1] + sm[2] + sm[3];
    float r = rsqrtf(ss * (1.f / 2048.f) + 1e-6f) * ps;
    float4 g0 = ((const float4*)g)[tid * 2];
    float4 g1 = ((const float4*)g)[tid * 2 + 1];
    float n[8];
    n[0] = v[0] * r * g0.x; n[1] = v[1] * r * g0.y;
    n[2] = v[2] * r * g0.z; n[3] = v[3] * r * g0.w;
    n[4] = v[4] * r * g1.x; n[5] = v[5] * r * g1.y;
    n[6] = v[6] * r * g1.z; n[7] = v[7] * r * g1.w;
    int pi = (tid & 15) * 4;
    float4 c4 = *(const float4*)(cs + t * 64 + pi);
    float4 s4 = *(const float4*)(sn + t * 64 + pi);
    float o[8];
    o[0] = n[0] * c4.x - n[1] * s4.x; o[1] = n[0] * s4.x + n[1] * c4.x;
    o[2] = n[2] * c4.y - n[3] * s4.y; o[3] = n[2] * s4.y + n[3] * c4.y;
    o[4] = n[4] * c4.z - n[5] * s4.z; o[5] = n[4] * s4.z + n[5] * c4.z;
    o[6] = n[6] * c4.w - n[7] * s4.w; o[7] = n[6] * s4.w + n[7] * c4.w;
    uint4 out;
    out.x = (u32)f2b(o[0]) | ((u32)f2b(o[1]) << 16);
    out.y = (u32)f2b(o[2]) | ((u32)f2b(o[3]) << 16);
    out.z = (u32)f2b(o[4]) | ((u32)f2b(o[5]) << 16);
    out.w = (u32)f2b(o[6]) | ((u32)f2b(o[7]) << 16);
    ((uint4*)x)[tid] = out;
}

// ---------- V transpose: (b,t,h,d) bf16 -> Vt[b][h][d][t] bf16 ----------
__global__ __launch_bounds__(256) void vtrans(const u16* __restrict__ V,
                                              u16* __restrict__ Vt) {
    int bh = blockIdx.y;
    int b = bh >> 4, h = bh & 15;
    int t0 = blockIdx.x * 64;
    __shared__ u32 tile[64][133];
    int tid = threadIdx.x;
    int r = tid >> 2, seg = (tid & 3) * 32;
    const uint4* src =
        (const uint4*)(V + ((size_t)b * Tn + t0 + r) * Cn + h * HDn + seg);
#pragma unroll
    for (int i = 0; i < 4; i++) {
        uint4 u = src[i];
        u32 uu[4] = {u.x, u.y, u.z, u.w};
#pragma unroll
        for (int j = 0; j < 4; j++) {
            tile[r][seg + i * 8 + j * 2] = uu[j] & 0xffff;
            tile[r][seg + i * 8 + j * 2 + 1] = uu[j] >> 16;
        }
    }
    __syncthreads();
    int d = tid >> 1, tseg = (tid & 1) * 32;
    u16* dst = Vt + ((size_t)bh * HDn + d) * Tn + t0 + tseg;
#pragma unroll
    for (int i = 0; i < 4; i++) {
        u32 p0 = tile[tseg + i * 8 + 0][d] | (tile[tseg + i * 8 + 1][d] << 16);
        u32 p1 = tile[tseg + i * 8 + 2][d] | (tile[tseg + i * 8 + 3][d] << 16);
        u32 p2 = tile[tseg + i * 8 + 4][d] | (tile[tseg + i * 8 + 5][d] << 16);
        u32 p3 = tile[tseg + i * 8 + 6][d] | (tile[tseg + i * 8 + 7][d] << 16);
        ((uint4*)dst)[i] = make_uint4(p0, p1, p2, p3);
    }
}

// ---------- flash attention v2: no online max (scores bounded — Q,K are
// RMS-normalized; exp stays in fp32 range). Per-lane partial sums, one
// cross-lane reduce after the K-loop. Masking only in the boundary tile.
#define KS_S 136  // u16: 128 + 8 pad
#define VS_S 72   // u16: 64 + 8 pad
#define PS_S 72   // u16: 64 + 8 pad
__global__ __launch_bounds__(256) void flash(const u16* __restrict__ Qb,
                                             const u16* __restrict__ Kb,
                                             const u16* __restrict__ Vt,
                                             const int* __restrict__ mask,
                                             float* __restrict__ O) {
    int qt = blockIdx.x, bh = blockIdx.y;
    int b = bh >> 4, h = bh & 15;
    int L = mask[b];
    int nkfull = L >> 6;
    int nk = (L + 63) >> 6;
    __shared__ u16 Ks[64 * KS_S];
    __shared__ u16 Vs[128 * VS_S];
    __shared__ u16 Ps[4][16 * PS_S];
    int tid = threadIdx.x, w = tid >> 6, lane = tid & 63;
    int quad = lane >> 4, l15 = lane & 15;
    const u16* qrow =
        Qb + ((size_t)b * Tn + qt * 64 + w * 16 + l15) * Cn + h * HDn;
    v8s aq[4];
#pragma unroll
    for (int kk = 0; kk < 4; kk++)
        aq[kk] = *(const v8s*)(qrow + kk * 32 + quad * 8);
    float sum[4] = {0.f, 0.f, 0.f, 0.f};
    const v4f zf = {0.f, 0.f, 0.f, 0.f};
    v4f oacc[8];
#pragma unroll
    for (int i = 0; i < 8; i++) oacc[i] = zf;
    for (int kt = 0; kt < nk; kt++) {
        int kb0 = kt * 64;
        {
            int r = tid >> 2, seg = (tid & 3) * 32;
            const uint4* src = (const uint4*)(Kb + ((size_t)b * Tn + kb0 + r) * Cn +
                                              h * HDn + seg);
            uint4* dst = (uint4*)(Ks + r * KS_S + seg);
#pragma unroll
            for (int i = 0; i < 4; i++) dst[i] = src[i];
        }
        {
            int d = tid >> 1, seg = (tid & 1) * 32;
            const uint4* src =
                (const uint4*)(Vt + ((size_t)bh * HDn + d) * Tn + kb0 + seg);
            uint4* dst = (uint4*)(Vs + d * VS_S + seg);
#pragma unroll
            for (int i = 0; i < 4; i++) dst[i] = src[i];
        }
        __syncthreads();
        v4f sacc[4];
#pragma unroll
        for (int nj = 0; nj < 4; nj++) sacc[nj] = zf;
#pragma unroll
        for (int kk = 0; kk < 4; kk++) {
#pragma unroll
            for (int nj = 0; nj < 4; nj++) {
                v8s bk =
                    *(const v8s*)(Ks + (nj * 16 + l15) * KS_S + kk * 32 + quad * 8);
                sacc[nj] = __builtin_amdgcn_mfma_f32_16x16x32_bf16(aq[kk], bk,
                                                                   sacc[nj], 0, 0, 0);
            }
        }
        u16 pb[4][4];
        if (kt < nkfull) {  // full tile: no masking
#pragma unroll
            for (int nj = 0; nj < 4; nj++)
#pragma unroll
                for (int r2 = 0; r2 < 4; r2++) {
                    float p = __expf(sacc[nj][r2]);  // scale folded into Q
                    sum[r2] += p;
                    pb[nj][r2] = f2b(p);
                }
        } else {  // boundary tile
#pragma unroll
            for (int nj = 0; nj < 4; nj++) {
                bool valid = (kb0 + nj * 16 + l15) < L;
#pragma unroll
                for (int r2 = 0; r2 < 4; r2++) {
                    float p = valid ? __expf(sacc[nj][r2]) : 0.f;
                    sum[r2] += p;
                    pb[nj][r2] = f2b(p);
                }
            }
        }
        u16* pw = &Ps[w][0];
#pragma unroll
        for (int nj = 0; nj < 4; nj++)
#pragma unroll
            for (int r2 = 0; r2 < 4; r2++)
                pw[(quad * 4 + r2) * PS_S + nj * 16 + l15] = pb[nj][r2];
        asm volatile("s_waitcnt lgkmcnt(0)" ::: "memory");
#pragma unroll
        for (int kk2 = 0; kk2 < 2; kk2++) {
            v8s ap = *(const v8s*)(pw + l15 * PS_S + kk2 * 32 + quad * 8);
#pragma unroll
            for (int nj2 = 0; nj2 < 8; nj2++) {
                v8s bv =
                    *(const v8s*)(Vs + (nj2 * 16 + l15) * VS_S + kk2 * 32 + quad * 8);
                oacc[nj2] = __builtin_amdgcn_mfma_f32_16x16x32_bf16(ap, bv, oacc[nj2],
                                                                    0, 0, 0);
            }
        }
        __syncthreads();
    }
    // cross-lane row-sum reduction (once): rows live in l15 within each quad
    float inv4[4];
#pragma unroll
    for (int r2 = 0; r2 < 4; r2++) {
        float s2 = sum[r2];
#pragma unroll
        for (int o = 8; o; o >>= 1) s2 += __shfl_xor(s2, o);
        inv4[r2] = 1.f / s2;
    }
#pragma unroll
    for (int nj2 = 0; nj2 < 8; nj2++) {
        int d = h * HDn + nj2 * 16 + l15;
#pragma unroll
        for (int r2 = 0; r2 < 4; r2++) {
            int q = qt * 64 + w * 16 + quad * 4 + r2;
            O[((size_t)b * Tn + q) * Cn + d] = oacc[nj2][r2] * inv4[r2];
        }
    }
}

extern "C" void kernel_launch(void* const* d_in, const int* in_sizes, int n_in,
                              void* d_out, int out_size, void* d_ws,
                              size_t ws_size, hipStream_t stream) {
    const float* hidden = (const float*)d_in[0];
    const int* mask = (const int*)d_in[1];
    const float* wq = (const float*)d_in[2];
    const float* wk = (const float*)d_in[3];
    const float* wv = (const float*)d_in[4];
    const float* wo = (const float*)d_in[5];
    const float* qg = (const float*)d_in[6];
    const float* kg = (const float*)d_in[7];
    const float* cs = (const float*)d_in[8];
    const float* sn = (const float*)d_in[9];

    char* ws = (char*)d_ws;
    int8_t* q8 = (int8_t*)(ws);                  // 24 MiB: wq,wk,wv,wo (4MiB ea) + hidden (8MiB)
    float* sAll = (float*)(ws + 25165824);       // 12288 fp32 (weights + hidden scales)
    u16* qb = (u16*)(ws + 25214976);             // Q bf16 (B,T,C)
    u16* kb = (u16*)(ws + 41992192);             // K bf16
    u16* vb = (u16*)(ws + 58769408);             // V bf16
    u16* vt = (u16*)(ws + 75546624);             // V^T bf16 (B,H,HD,T)
    float* Obuf = (float*)(ws + 92323840);       // O fp32 (B,T,C)
    // total ws use: 125,878,272 bytes
    int8_t* hid8 = q8 + 16777216;                // hidden int8 (reused for O)
    float* sx = sAll + 8192;                     // hidden scales (reused for O)

    quant_all<<<12288, 256, 0, stream>>>(wq, wk, wv, wo, hidden, q8, sAll);

    gemm_i8<<<dim3(32, 16, 3), 256, 0, stream>>>(hid8, q8, sx, sAll, (void*)qb,
                                                 4194304LL, 2048LL, 8388608LL, 0);

    norm_rope2<<<8192, 256, 0, stream>>>(qb, kb, qg, kg, cs, sn);
    vtrans<<<dim3(32, 32), 256, 0, stream>>>(vb, vt);

    flash<<<dim3(32, 32), 256, 0, stream>>>(qb, kb, vt, mask, Obuf);

    quant_rows<<<4096, 256, 0, stream>>>(Obuf, hid8, sx);
    gemm_i8<<<dim3(32, 16, 1), 256, 0, stream>>>(hid8, q8 + 12582912, sx,
                                                 sAll + 6144, d_out, 0LL, 0LL,
                                                 0LL, 1);
}

// Round 6
// 351.680 us; speedup vs baseline: 1.3644x; 1.0122x over previous
//
#include <hip/hip_runtime.h>
#include <stdint.h>

typedef unsigned short u16;
typedef unsigned int u32;
typedef int v4i __attribute__((ext_vector_type(4)));
typedef float v4f __attribute__((ext_vector_type(4)));
typedef short v8s __attribute__((ext_vector_type(8)));

#define Bn 2
#define Tn 2048
#define Cn 2048
#define Hn 16
#define HDn 128

__device__ __forceinline__ float b2f(u16 u) {
    u32 x = ((u32)u) << 16;
    float f;
    __builtin_memcpy(&f, &x, 4);
    return f;
}
__device__ __forceinline__ u16 f2b(float f) {
    u32 x;
    __builtin_memcpy(&x, &f, 4);
    u32 r = (x + 0x7fffu + ((x >> 16) & 1u)) >> 16;
    return (u16)r;
}

__device__ __forceinline__ void async16(const void* g, void* l) {
    __builtin_amdgcn_global_load_lds(
        (const __attribute__((address_space(1))) u32*)g,
        (__attribute__((address_space(3))) u32*)l, 16, 0, 0);
}

// ---------- fused row quantization: 4 weight matrices + hidden ----------
__global__ __launch_bounds__(256) void quant_all(
    const float* __restrict__ w0, const float* __restrict__ w1,
    const float* __restrict__ w2, const float* __restrict__ w3,
    const float* __restrict__ hid, int8_t* __restrict__ Q,
    float* __restrict__ S) {
    int r = blockIdx.x;
    const float* src;
    int ro;
    if (r < 2048) { src = w0; ro = r; }
    else if (r < 4096) { src = w1; ro = r - 2048; }
    else if (r < 6144) { src = w2; ro = r - 4096; }
    else if (r < 8192) { src = w3; ro = r - 6144; }
    else { src = hid; ro = r - 8192; }
    const float* x = src + (size_t)ro * Cn;
    int tid = threadIdx.x;
    float4 v0 = ((const float4*)x)[tid * 2];
    float4 v1 = ((const float4*)x)[tid * 2 + 1];
    float a[8] = {v0.x, v0.y, v0.z, v0.w, v1.x, v1.y, v1.z, v1.w};
    float m = 0.f;
#pragma unroll
    for (int i = 0; i < 8; i++) m = fmaxf(m, fabsf(a[i]));
#pragma unroll
    for (int o = 32; o; o >>= 1) m = fmaxf(m, __shfl_xor(m, o));
    __shared__ float sm[4];
    if ((tid & 63) == 0) sm[tid >> 6] = m;
    __syncthreads();
    m = fmaxf(fmaxf(sm[0], sm[1]), fmaxf(sm[2], sm[3]));
    float s = m * (1.0f / 127.0f) + 1e-8f;
    if (tid == 0) S[r] = s;
    u32 lo = 0, hi = 0;
#pragma unroll
    for (int i = 0; i < 8; i++) {
        float q = rintf(fminf(127.f, fmaxf(-127.f, a[i] / s)));
        int qi = (int)q;
        u32 byte = (u32)(qi & 0xff);
        if (i < 4) lo |= byte << (8 * i);
        else hi |= byte << (8 * (i - 4));
    }
    u32* qp = (u32*)(Q + (size_t)r * Cn);
    qp[tid * 2] = lo;
    qp[tid * 2 + 1] = hi;
}

// ---------- row quantization (fp32, attention output O) ----------
__global__ __launch_bounds__(256) void quant_rows(const float* __restrict__ X,
                                                  int8_t* __restrict__ Q,
                                                  float* __restrict__ S) {
    int r = blockIdx.x;
    const float* x = X + (size_t)r * Cn;
    int tid = threadIdx.x;
    float4 v0 = ((const float4*)x)[tid * 2];
    float4 v1 = ((const float4*)x)[tid * 2 + 1];
    float a[8] = {v0.x, v0.y, v0.z, v0.w, v1.x, v1.y, v1.z, v1.w};
    float m = 0.f;
#pragma unroll
    for (int i = 0; i < 8; i++) m = fmaxf(m, fabsf(a[i]));
#pragma unroll
    for (int o = 32; o; o >>= 1) m = fmaxf(m, __shfl_xor(m, o));
    __shared__ float sm[4];
    if ((tid & 63) == 0) sm[tid >> 6] = m;
    __syncthreads();
    m = fmaxf(fmaxf(sm[0], sm[1]), fmaxf(sm[2], sm[3]));
    float s = m * (1.0f / 127.0f) + 1e-8f;
    if (tid == 0) S[r] = s;
    u32 lo = 0, hi = 0;
#pragma unroll
    for (int i = 0; i < 8; i++) {
        float q = rintf(fminf(127.f, fmaxf(-127.f, a[i] / s)));
        int qi = (int)q;
        u32 byte = (u32)(qi & 0xff);
        if (i < 4) lo |= byte << (8 * i);
        else hi |= byte << (8 * (i - 4));
    }
    u32* qp = (u32*)(Q + (size_t)r * Cn);
    qp[tid * 2] = lo;
    qp[tid * 2 + 1] = hi;
}

// ---------- int8 GEMM (unchanged from R5) ----------
__global__ __launch_bounds__(256) void gemm_i8(
    const int8_t* __restrict__ A, const int8_t* __restrict__ Bw,
    const float* __restrict__ sA, const float* __restrict__ sB,
    void* __restrict__ Co, long long bStride, long long sbStride,
    long long cStride, int fp32out) {
    int z = blockIdx.z;
    Bw += (size_t)z * bStride;
    sB += (size_t)z * sbStride;
    const int K = 2048, N = 2048;
    __shared__ int8_t As[128 * 64];
    __shared__ int8_t Bs[128 * 64];
    int m0 = blockIdx.x * 128, n0 = blockIdx.y * 128;
    int tid = threadIdx.x, w = tid >> 6, lane = tid & 63;
    int quad = lane >> 4, l15 = lane & 15;
    int wy = w >> 1, wx = w & 1;
    const v4i zi = {0, 0, 0, 0};
    v4i acc[4][4];
#pragma unroll
    for (int i = 0; i < 4; i++)
#pragma unroll
        for (int j = 0; j < 4; j++) acc[i][j] = zi;
    int lrow = lane >> 2;
    int slot = lane & 3;
    int srow = w * 32 + lrow;
    int klog = ((slot ^ (lrow & 3)) * 16);
    const int8_t* ga = A + (size_t)(m0 + srow) * K + klog;
    const int8_t* gb = Bw + (size_t)(n0 + srow) * K + klog;
    int8_t* la = &As[srow * 64 + slot * 16];
    int8_t* lb = &Bs[srow * 64 + slot * 16];
    for (int k0 = 0; k0 < K; k0 += 64) {
        async16(ga + k0, la);
        async16(ga + k0 + (size_t)16 * K, la + 16 * 64);
        async16(gb + k0, lb);
        async16(gb + k0 + (size_t)16 * K, lb + 16 * 64);
        __syncthreads();
        int swz = (quad ^ (l15 & 3)) * 16;
        v4i af[4], bf4[4];
#pragma unroll
        for (int i = 0; i < 4; i++)
            af[i] = *(const v4i*)&As[(wy * 64 + i * 16 + l15) * 64 + swz];
#pragma unroll
        for (int j = 0; j < 4; j++)
            bf4[j] = *(const v4i*)&Bs[(wx * 64 + j * 16 + l15) * 64 + swz];
#pragma unroll
        for (int i = 0; i < 4; i++)
#pragma unroll
            for (int j = 0; j < 4; j++)
                acc[i][j] = __builtin_amdgcn_mfma_i32_16x16x64_i8(
                    af[i], bf4[j], acc[i][j], 0, 0, 0);
        __syncthreads();
    }
#pragma unroll
    for (int i = 0; i < 4; i++) {
        int mb = m0 + wy * 64 + i * 16 + quad * 4;
        float s0 = sA[mb], s1 = sA[mb + 1], s2 = sA[mb + 2], s3 = sA[mb + 3];
#pragma unroll
        for (int j = 0; j < 4; j++) {
            int n = n0 + wx * 64 + j * 16 + l15;
            float sb = sB[n];
            if (fp32out) {
                float* cp = (float*)Co + (size_t)cStride * z + (size_t)mb * N + n;
                cp[0] = (float)acc[i][j][0] * s0 * sb;
                cp[N] = (float)acc[i][j][1] * s1 * sb;
                cp[2 * N] = (float)acc[i][j][2] * s2 * sb;
                cp[3 * N] = (float)acc[i][j][3] * s3 * sb;
            } else {
                u16* cp = (u16*)Co + (size_t)cStride * z + (size_t)mb * N + n;
                cp[0] = f2b((float)acc[i][j][0] * s0 * sb);
                cp[N] = f2b((float)acc[i][j][1] * s1 * sb);
                cp[2 * N] = f2b((float)acc[i][j][2] * s2 * sb);
                cp[3 * N] = f2b((float)acc[i][j][3] * s3 * sb);
            }
        }
    }
}

// ---------- fused RMSNorm + RoPE (Q gets 1/sqrt(HD) folded) ----------
__global__ __launch_bounds__(256) void norm_rope2(u16* __restrict__ Qb,
                                                  u16* __restrict__ Kb,
                                                  const float* __restrict__ qg,
                                                  const float* __restrict__ kg,
                                                  const float* __restrict__ cs,
                                                  const float* __restrict__ sn) {
    int row = blockIdx.x;
    int isq = row < 4096;
    row &= 4095;
    u16* x = (isq ? Qb : Kb) + (size_t)row * Cn;
    const float* g = isq ? qg : kg;
    float ps = isq ? 0.08838834764831845f : 1.0f;
    int t = row & (Tn - 1);
    int tid = threadIdx.x;
    uint4 raw = ((const uint4*)x)[tid];
    u16 us[8];
    us[0] = raw.x & 0xffff; us[1] = raw.x >> 16;
    us[2] = raw.y & 0xffff; us[3] = raw.y >> 16;
    us[4] = raw.z & 0xffff; us[5] = raw.z >> 16;
    us[6] = raw.w & 0xffff; us[7] = raw.w >> 16;
    float v[8];
#pragma unroll
    for (int i = 0; i < 8; i++) v[i] = b2f(us[i]);
    float ss = 0.f;
#pragma unroll
    for (int i = 0; i < 8; i++) ss += v[i] * v[i];
#pragma unroll
    for (int o = 32; o; o >>= 1) ss += __shfl_xor(ss, o);
    __shared__ float sm[4];
    if ((tid & 63) == 0) sm[tid >> 6] = ss;
    __syncthreads();
    ss = sm[0] + sm[1] + sm[2] + sm[3];
    float r = rsqrtf(ss * (1.f / 2048.f) + 1e-6f) * ps;
    float4 g0 = ((const float4*)g)[tid * 2];
    float4 g1 = ((const float4*)g)[tid * 2 + 1];
    float n[8];
    n[0] = v[0] * r * g0.x; n[1] = v[1] * r * g0.y;
    n[2] = v[2] * r * g0.z; n[3] = v[3] * r * g0.w;
    n[4] = v[4] * r * g1.x; n[5] = v[5] * r * g1.y;
    n[6] = v[6] * r * g1.z; n[7] = v[7] * r * g1.w;
    int pi = (tid & 15) * 4;
    float4 c4 = *(const float4*)(cs + t * 64 + pi);
    float4 s4 = *(const float4*)(sn + t * 64 + pi);
    float o[8];
    o[0] = n[0] * c4.x - n[1] * s4.x; o[1] = n[0] * s4.x + n[1] * c4.x;
    o[2] = n[2] * c4.y - n[3] * s4.y; o[3] = n[2] * s4.y + n[3] * c4.y;
    o[4] = n[4] * c4.z - n[5] * s4.z; o[5] = n[4] * s4.z + n[5] * c4.z;
    o[6] = n[6] * c4.w - n[7] * s4.w; o[7] = n[6] * s4.w + n[7] * c4.w;
    uint4 out;
    out.x = (u32)f2b(o[0]) | ((u32)f2b(o[1]) << 16);
    out.y = (u32)f2b(o[2]) | ((u32)f2b(o[3]) << 16);
    out.z = (u32)f2b(o[4]) | ((u32)f2b(o[5]) << 16);
    out.w = (u32)f2b(o[6]) | ((u32)f2b(o[7]) << 16);
    ((uint4*)x)[tid] = out;
}

// ---------- V transpose: (b,t,h,d) bf16 -> Vt[b][h][d][t] ----------
__global__ __launch_bounds__(256) void vtrans(const u16* __restrict__ V,
                                              u16* __restrict__ Vt) {
    int bh = blockIdx.y;
    int b = bh >> 4, h = bh & 15;
    int t0 = blockIdx.x * 64;
    __shared__ u32 tile[64][133];
    int tid = threadIdx.x;
    int r = tid >> 2, seg = (tid & 3) * 32;
    const uint4* src =
        (const uint4*)(V + ((size_t)b * Tn + t0 + r) * Cn + h * HDn + seg);
#pragma unroll
    for (int i = 0; i < 4; i++) {
        uint4 u = src[i];
        u32 uu[4] = {u.x, u.y, u.z, u.w};
#pragma unroll
        for (int j = 0; j < 4; j++) {
            tile[r][seg + i * 8 + j * 2] = uu[j] & 0xffff;
            tile[r][seg + i * 8 + j * 2 + 1] = uu[j] >> 16;
        }
    }
    __syncthreads();
    int d = tid >> 1, tseg = (tid & 1) * 32;
    u16* dst = Vt + ((size_t)bh * HDn + d) * Tn + t0 + tseg;
#pragma unroll
    for (int i = 0; i < 4; i++) {
        u32 p0 = tile[tseg + i * 8 + 0][d] | (tile[tseg + i * 8 + 1][d] << 16);
        u32 p1 = tile[tseg + i * 8 + 2][d] | (tile[tseg + i * 8 + 3][d] << 16);
        u32 p2 = tile[tseg + i * 8 + 4][d] | (tile[tseg + i * 8 + 5][d] << 16);
        u32 p3 = tile[tseg + i * 8 + 6][d] | (tile[tseg + i * 8 + 7][d] << 16);
        ((uint4*)dst)[i] = make_uint4(p0, p1, p2, p3);
    }
}

// ---------- flash v3: wave-split K/V ownership, async XOR-swizzled staging
// Wave w: QK for keys [w*16, w*16+16) over ALL 64 q (Q frags in regs);
//         PV for d-blocks {2w, 2w+1} over all q.
// LDS flat, reads conflict-free via phys_group = logical ^ (row&7).
__global__ __launch_bounds__(256, 3) void flash(const u16* __restrict__ Qb,
                                                const u16* __restrict__ Kb,
                                                const u16* __restrict__ Vt,
                                                const int* __restrict__ mask,
                                                float* __restrict__ O) {
    int qt = blockIdx.x, bh = blockIdx.y;
    int b = bh >> 4, h = bh & 15;
    int L = mask[b];
    int nkfull = L >> 6;
    int nk = (L + 63) >> 6;
    __shared__ u16 Ks[64 * 128];
    __shared__ u16 Vs[128 * 64];
    __shared__ u16 Ps[64 * 72];
    __shared__ float sred[256];
    __shared__ float sinv[64];
    int tid = threadIdx.x, w = tid >> 6, lane = tid & 63;
    int quad = lane >> 4, l15 = lane & 15;

    // Q A-fragments: all 4 m-blocks (q rows qt*64 + i*16 + l15)
    v8s aq[4][4];
#pragma unroll
    for (int i = 0; i < 4; i++)
#pragma unroll
        for (int kk = 0; kk < 4; kk++)
            aq[i][kk] = *(const v8s*)(Qb +
                                      ((size_t)b * Tn + qt * 64 + i * 16 + l15) * Cn +
                                      h * HDn + kk * 32 + quad * 8);

    // async staging geometry (XOR source gather -> conflict-free reads)
    const u16* ksp[4];
    u16* kdp[4];
    const u16* vsp[4];
    u16* vdp[4];
#pragma unroll
    for (int cc = 0; cc < 4; cc++) {
        int c = w * 4 + cc;
        int rk = c * 4 + (lane >> 4);
        int sk = lane & 15;
        int lgk = sk ^ (rk & 7);
        ksp[cc] = Kb + ((size_t)b * Tn + rk) * Cn + h * HDn + lgk * 8;
        kdp[cc] = Ks + rk * 128 + sk * 8;
        int rv = c * 8 + (lane >> 3);
        int sv = lane & 7;
        int lgv = sv ^ (rv & 7);
        vsp[cc] = Vt + ((size_t)bh * HDn + rv) * Tn + lgv * 8;
        vdp[cc] = Vs + rv * 64 + sv * 8;
    }

    float sum16[16];
#pragma unroll
    for (int j = 0; j < 16; j++) sum16[j] = 0.f;
    const v4f zf = {0.f, 0.f, 0.f, 0.f};
    v4f oacc[4][2];
#pragma unroll
    for (int m = 0; m < 4; m++) {
        oacc[m][0] = zf;
        oacc[m][1] = zf;
    }
    int swz = ((l15 & 7) ^ quad) << 3;  // phys col offset for quad group, kk=0

    for (int kt = 0; kt < nk; kt++) {
        __syncthreads();  // previous tile fully consumed
#pragma unroll
        for (int cc = 0; cc < 4; cc++) async16(ksp[cc], kdp[cc]);
#pragma unroll
        for (int cc = 0; cc < 4; cc++) async16(vsp[cc], vdp[cc]);
#pragma unroll
        for (int cc = 0; cc < 4; cc++) {
            ksp[cc] += 64 * Cn;
            vsp[cc] += 64;
        }
        __syncthreads();  // staged (vmcnt drained by compiler before barrier)
        // QK^T: this wave's 16 keys
        v4f sacc[4] = {zf, zf, zf, zf};
        const u16* krow = Ks + (w * 16 + l15) * 128;
#pragma unroll
        for (int kk = 0; kk < 4; kk++) {
            v8s bk = *(const v8s*)(krow + ((((kk * 4 + quad) ^ (l15 & 7))) << 3));
#pragma unroll
            for (int i = 0; i < 4; i++)
                sacc[i] = __builtin_amdgcn_mfma_f32_16x16x32_bf16(aq[i][kk], bk,
                                                                  sacc[i], 0, 0, 0);
        }
        bool valid = (kt < nkfull) || ((kt * 64 + w * 16 + l15) < L);
#pragma unroll
        for (int i = 0; i < 4; i++)
#pragma unroll
            for (int r2 = 0; r2 < 4; r2++) {
                float p = valid ? __expf(sacc[i][r2]) : 0.f;
                sum16[i * 4 + r2] += p;
                Ps[(i * 16 + quad * 4 + r2) * 72 + w * 16 + l15] = f2b(p);
            }
        __syncthreads();  // P visible to all waves
        // PV: this wave's two d-blocks
#pragma unroll
        for (int kk2 = 0; kk2 < 2; kk2++) {
            v8s ap[4];
#pragma unroll
            for (int m = 0; m < 4; m++)
                ap[m] = *(const v8s*)(Ps + (m * 16 + l15) * 72 + kk2 * 32 + quad * 8);
#pragma unroll
            for (int nbi = 0; nbi < 2; nbi++) {
                int vr = (2 * w + nbi) * 16 + l15;
                v8s bv = *(const v8s*)(Vs + vr * 64 +
                                       ((((kk2 * 4 + quad) ^ (l15 & 7))) << 3));
#pragma unroll
                for (int m = 0; m < 4; m++)
                    oacc[m][nbi] = __builtin_amdgcn_mfma_f32_16x16x32_bf16(
                        ap[m], bv, oacc[m][nbi], 0, 0, 0);
            }
        }
    }
    // softmax denominators: reduce over this wave's 16 keys (l15 lanes)...
#pragma unroll
    for (int j = 0; j < 16; j++) {
        float s = sum16[j];
        s += __shfl_xor(s, 1);
        s += __shfl_xor(s, 2);
        s += __shfl_xor(s, 4);
        s += __shfl_xor(s, 8);
        sum16[j] = s;
    }
    if (l15 == 0) {
#pragma unroll
        for (int i = 0; i < 4; i++)
#pragma unroll
            for (int r2 = 0; r2 < 4; r2++)
                sred[w * 64 + i * 16 + quad * 4 + r2] = sum16[i * 4 + r2];
    }
    __syncthreads();
    // ...then across the 4 waves' key blocks
    if (tid < 64)
        sinv[tid] =
            1.f / (sred[tid] + sred[64 + tid] + sred[128 + tid] + sred[192 + tid]);
    __syncthreads();
#pragma unroll
    for (int m = 0; m < 4; m++)
#pragma unroll
        for (int r2 = 0; r2 < 4; r2++) {
            float inv = sinv[m * 16 + quad * 4 + r2];
            int row = qt * 64 + m * 16 + quad * 4 + r2;
#pragma unroll
            for (int nbi = 0; nbi < 2; nbi++) {
                int d = h * HDn + (2 * w + nbi) * 16 + l15;
                O[((size_t)b * Tn + row) * Cn + d] = oacc[m][nbi][r2] * inv;
            }
        }
    (void)swz;
}

extern "C" void kernel_launch(void* const* d_in, const int* in_sizes, int n_in,
                              void* d_out, int out_size, void* d_ws,
                              size_t ws_size, hipStream_t stream) {
    const float* hidden = (const float*)d_in[0];
    const int* mask = (const int*)d_in[1];
    const float* wq = (const float*)d_in[2];
    const float* wk = (const float*)d_in[3];
    const float* wv = (const float*)d_in[4];
    const float* wo = (const float*)d_in[5];
    const float* qg = (const float*)d_in[6];
    const float* kg = (const float*)d_in[7];
    const float* cs = (const float*)d_in[8];
    const float* sn = (const float*)d_in[9];

    char* ws = (char*)d_ws;
    int8_t* q8 = (int8_t*)(ws);                  // 24 MiB: wq,wk,wv,wo + hidden
    float* sAll = (float*)(ws + 25165824);       // 12288 fp32 scales
    u16* qb = (u16*)(ws + 25214976);             // Q bf16 (B,T,C)
    u16* kb = (u16*)(ws + 41992192);             // K bf16
    u16* vb = (u16*)(ws + 58769408);             // V bf16
    u16* vt = (u16*)(ws + 75546624);             // V^T bf16 (B,H,HD,T)
    float* Obuf = (float*)(ws + 92323840);       // O fp32 (B,T,C)
    int8_t* hid8 = q8 + 16777216;                // hidden int8 (reused for O)
    float* sx = sAll + 8192;                     // hidden scales (reused for O)

    quant_all<<<12288, 256, 0, stream>>>(wq, wk, wv, wo, hidden, q8, sAll);

    gemm_i8<<<dim3(32, 16, 3), 256, 0, stream>>>(hid8, q8, sx, sAll, (void*)qb,
                                                 4194304LL, 2048LL, 8388608LL, 0);

    norm_rope2<<<8192, 256, 0, stream>>>(qb, kb, qg, kg, cs, sn);
    vtrans<<<dim3(32, 32), 256, 0, stream>>>(vb, vt);

    flash<<<dim3(32, 32), 256, 0, stream>>>(qb, kb, vt, mask, Obuf);

    quant_rows<<<4096, 256, 0, stream>>>(Obuf, hid8, sx);
    gemm_i8<<<dim3(32, 16, 1), 256, 0, stream>>>(hid8, q8 + 12582912, sx,
                                                 sAll + 6144, d_out, 0LL, 0LL,
                                                 0LL, 1);
}